// Round 4
// baseline (372.251 us; speedup 1.0000x reference)
//
#include <hip/hip_runtime.h>
#include <math.h>

#define IDIM 1024
#define EDIM 256
#define NB 4
#define NT 2048
#define NROW 8192

typedef __attribute__((ext_vector_type(8))) short short8;
typedef __attribute__((ext_vector_type(4))) float f32x4;

#define MFMA16(A,B,C) __builtin_amdgcn_mfma_f32_16x16x32_bf16(A,B,C,0,0,0)
#define GLD16(gsrc, ldst) __builtin_amdgcn_global_load_lds( \
    (const __attribute__((address_space(1))) unsigned int*)(gsrc), \
    (__attribute__((address_space(3))) unsigned int*)(ldst), 16, 0, 0)

__device__ __forceinline__ unsigned short f2bf(float x){
    unsigned u = __builtin_bit_cast(unsigned, x);
    u += 0x7fffu + ((u >> 16) & 1u);
    return (unsigned short)(u >> 16);
}
__device__ __forceinline__ float bf2f(unsigned short h){
    unsigned u = ((unsigned)h) << 16;
    return __builtin_bit_cast(float, u);
}

// ---------------- split W -> W^T hi/lo bf16 ----------------
__global__ __launch_bounds__(256) void split_w(
    const float* __restrict__ Wq, const float* __restrict__ Wk, const float* __restrict__ Wv,
    ushort* __restrict__ Wqh, ushort* __restrict__ Wql,
    ushort* __restrict__ Wkh, ushort* __restrict__ Wkl,
    ushort* __restrict__ Wvh)
{
    int u = blockIdx.x * 256 + threadIdx.x;
    int z   = u >> 15;
    int rem = u & 32767;
    int ko  = rem >> 8;
    int e   = rem & 255;
    const float* W = (z == 0) ? Wq : (z == 1) ? Wk : Wv;
    ushort* Oh = (z == 0) ? Wqh : (z == 1) ? Wkh : Wvh;
    ushort* Ol = (z == 0) ? Wql : Wkl;
    union { ushort us[8]; uint4 v; } hi, lo;
    #pragma unroll
    for (int j = 0; j < 8; ++j) {
        float wv = W[(size_t)(ko * 8 + j) * 256 + e];
        unsigned short h = f2bf(wv);
        hi.us[j] = h;
        lo.us[j] = f2bf(wv - bf2f(h));
    }
    *(uint4*)(Oh + (size_t)e * 1024 + ko * 8) = hi.v;
    if (z < 2) *(uint4*)(Ol + (size_t)e * 1024 + ko * 8) = lo.v;
}

// ---------------- QKV projection: 64x128 tile, fused X-split, GLD16 for W ----------------
// grid (2 n-tiles, 128 m-tiles, 3 z). Wave w: n-strip w*32..+31, full M=64.
__global__ __launch_bounds__(256, 3) void qkv_proj(
    const float* __restrict__ X,
    const ushort* __restrict__ Whq, const ushort* __restrict__ Wlq,
    const ushort* __restrict__ Whk, const ushort* __restrict__ Wlk,
    const ushort* __restrict__ Whv,
    const float* __restrict__ bq, const float* __restrict__ bk, const float* __restrict__ bv,
    ushort* __restrict__ Qh, ushort* __restrict__ Ql,
    ushort* __restrict__ Kh, ushort* __restrict__ Kl,
    ushort* __restrict__ Vt)
{
    __shared__ ushort Ah[259 * 8], Al[259 * 8];   // unit = kq*65 + m (pad 65 vs 64)
    __shared__ ushort Bh[512 * 8], Bl[512 * 8];   // unit = kq*128 + n

    const int tid = threadIdx.x;
    const int lane = tid & 63, w = tid >> 6;
    const int ln = tid & 15, quad = (tid >> 4) & 3;
    const int z = blockIdx.z;
    const int n0 = blockIdx.x * 128, m0 = blockIdx.y * 64;
    const ushort* Wh = (z == 0) ? Whq : (z == 1) ? Whk : Whv;
    const ushort* Wl = (z == 0) ? Wlq : Wlk;

    f32x4 acc[4][2];
    #pragma unroll
    for (int mi = 0; mi < 4; ++mi)
        #pragma unroll
        for (int ni = 0; ni < 2; ++ni) acc[mi][ni] = (f32x4){0.f, 0.f, 0.f, 0.f};

    const int am = tid >> 2, ak8 = (tid & 3) * 8;
    const float* xp = X + (size_t)(m0 + am) * IDIM + ak8;
    const ushort* bsrc0 = Wh + (size_t)(n0 + lane) * IDIM + w * 8;
    const ushort* bsrc1 = Wh + (size_t)(n0 + 64 + lane) * IDIM + w * 8;
    const ushort* blsrc0 = Wl + (size_t)(n0 + lane) * IDIM + w * 8;
    const ushort* blsrc1 = Wl + (size_t)(n0 + 64 + lane) * IDIM + w * 8;
    ushort* bd0 = Bh + (size_t)(w * 128) * 8;
    ushort* bd1 = Bh + (size_t)(w * 128 + 64) * 8;
    ushort* bld0 = Bl + (size_t)(w * 128) * 8;
    ushort* bld1 = Bl + (size_t)(w * 128 + 64) * 8;

    for (int kk = 0; kk < IDIM; kk += 32) {
        GLD16(bsrc0 + kk, bd0);
        GLD16(bsrc1 + kk, bd1);
        if (z < 2) { GLD16(blsrc0 + kk, bld0); GLD16(blsrc1 + kk, bld1); }
        {   // A: read 8 f32 of X, split hi/lo, scatter fragment-major
            float4 a0 = *(const float4*)(xp + kk);
            float4 a1 = *(const float4*)(xp + kk + 4);
            float xv[8] = {a0.x, a0.y, a0.z, a0.w, a1.x, a1.y, a1.z, a1.w};
            union { ushort us[8]; uint4 v; } hi, lo;
            #pragma unroll
            for (int j = 0; j < 8; ++j) {
                unsigned short hh = f2bf(xv[j]);
                hi.us[j] = hh;
                lo.us[j] = f2bf(xv[j] - bf2f(hh));
            }
            int unit = (tid & 3) * 65 + am;
            *(uint4*)(Ah + unit * 8) = hi.v;
            if (z < 2) *(uint4*)(Al + unit * 8) = lo.v;
        }
        __syncthreads();

        short8 ah[4], al4[4];
        #pragma unroll
        for (int mi = 0; mi < 4; ++mi) {
            int au = quad * 65 + mi * 16 + ln;
            ah[mi] = *(const short8*)(Ah + au * 8);
            if (z < 2) al4[mi] = *(const short8*)(Al + au * 8);
        }
        #pragma unroll
        for (int ni = 0; ni < 2; ++ni) {
            int bu = quad * 128 + w * 32 + ni * 16 + ln;
            short8 bh = *(const short8*)(Bh + bu * 8);
            if (z < 2) {
                short8 bl = *(const short8*)(Bl + bu * 8);
                #pragma unroll
                for (int mi = 0; mi < 4; ++mi) {
                    acc[mi][ni] = MFMA16(ah[mi], bh, acc[mi][ni]);
                    acc[mi][ni] = MFMA16(ah[mi], bl, acc[mi][ni]);
                    acc[mi][ni] = MFMA16(al4[mi], bh, acc[mi][ni]);
                }
            } else {
                #pragma unroll
                for (int mi = 0; mi < 4; ++mi)
                    acc[mi][ni] = MFMA16(ah[mi], bh, acc[mi][ni]);
            }
        }
        __syncthreads();
    }

    if (z < 2) {
        ushort* OH = (z == 0) ? Qh : Kh;
        ushort* OL = (z == 0) ? Ql : Kl;
        const float* bias = (z == 0) ? bq : bk;
        const float scale = (z == 0) ? 46.16624130844683f : 1.0f;  // 32*log2(e)
        #pragma unroll
        for (int ni = 0; ni < 2; ++ni) {
            int col = n0 + w * 32 + ni * 16 + ln;
            float bb = bias[col];
            #pragma unroll
            for (int mi = 0; mi < 4; ++mi)
                #pragma unroll
                for (int r = 0; r < 4; ++r) {
                    int row = m0 + mi * 16 + quad * 4 + r;
                    float v = (acc[mi][ni][r] + bb) * scale;
                    unsigned short hh = f2bf(v);
                    OH[(size_t)row * EDIM + col] = hh;
                    OL[(size_t)row * EDIM + col] = f2bf(v - bf2f(hh));
                }
        }
    } else {
        #pragma unroll
        for (int ni = 0; ni < 2; ++ni) {
            int col = n0 + w * 32 + ni * 16 + ln;
            float bb = bv[col];
            #pragma unroll
            for (int mi = 0; mi < 4; ++mi) {
                int rowb = m0 + mi * 16 + quad * 4;
                union { ushort us[4]; uint2 v; } pk;
                #pragma unroll
                for (int r = 0; r < 4; ++r) pk.us[r] = f2bf(acc[mi][ni][r] + bb);
                *(uint2*)(Vt + (size_t)col * NROW + rowb) = pk.v;
            }
        }
    }
}

// ---------------- attention: wave = 16 q x 256 kv, kv-split 8, in-block pair merge ----------------
// 1024 blocks x 4 waves; LDS 33 KB -> 4 blocks/CU. Block emits 1 bf16 partial (2/q-tile).
__global__ __launch_bounds__(256, 4) void attn(
    const ushort* __restrict__ Qh, const ushort* __restrict__ Ql,
    const ushort* __restrict__ Kh, const ushort* __restrict__ Kl,
    const ushort* __restrict__ Vt, ushort* __restrict__ Op, float* __restrict__ mlbuf)
{
    __shared__ ushort U[16384];            // front 4352: P slabs; whole: bf16 O_s reuse
    __shared__ float m_s[64], l_s[64];
    const int tid = threadIdx.x;
    const int ln = tid & 15, quad = (tid >> 4) & 3, w = tid >> 6;
    ushort* Pslab = U + w * 1088;          // unit = ko*17 + m

    const int id = blockIdx.x;
    const int b  = (id >> 1) & 3;          // XCD-locked batch
    const int h  = id & 1;                 // kv half (XCD-locked too)
    const int qt = id >> 3;                // 0..127
    const size_t qrow0 = (size_t)b * NT + (size_t)qt * 16;
    const int kvs = b * NT + h * 1024 + w * 256;

    const ushort* qbase  = Qh + (qrow0 + ln) * EDIM + quad * 8;
    const ushort* qlbase = Ql + (qrow0 + ln) * EDIM + quad * 8;

    float m_r[4], l_r[4];
    #pragma unroll
    for (int r = 0; r < 4; ++r) { m_r[r] = -3e38f; l_r[r] = 0.f; }
    f32x4 o[16];
    #pragma unroll
    for (int ni = 0; ni < 16; ++ni) o[ni] = (f32x4){0.f, 0.f, 0.f, 0.f};

    for (int t = 0; t < 4; ++t) {
        const int gkv = kvs + t * 64;
        f32x4 s[4];
        #pragma unroll
        for (int ni = 0; ni < 4; ++ni) s[ni] = (f32x4){0.f, 0.f, 0.f, 0.f};

        #pragma unroll
        for (int kc = 0; kc < 8; ++kc) {
            short8 qh8 = *(const short8*)(qbase + kc * 32);
            short8 ql8 = *(const short8*)(qlbase + kc * 32);
            #pragma unroll
            for (int ni = 0; ni < 4; ++ni) {
                size_t off = (size_t)(gkv + ni * 16 + ln) * EDIM + kc * 32 + quad * 8;
                short8 bh = *(const short8*)(Kh + off);
                short8 bl = *(const short8*)(Kl + off);
                s[ni] = MFMA16(qh8, bh, s[ni]);
                s[ni] = MFMA16(qh8, bl, s[ni]);
                s[ni] = MFMA16(ql8, bh, s[ni]);
            }
        }

        float mt[4];
        #pragma unroll
        for (int r = 0; r < 4; ++r)
            mt[r] = fmaxf(fmaxf(s[0][r], s[1][r]), fmaxf(s[2][r], s[3][r]));
        #pragma unroll
        for (int mask = 1; mask < 16; mask <<= 1)
            #pragma unroll
            for (int r = 0; r < 4; ++r)
                mt[r] = fmaxf(mt[r], __shfl_xor(mt[r], mask));
        float alpha[4];
        #pragma unroll
        for (int r = 0; r < 4; ++r) {
            float mn = fmaxf(m_r[r], mt[r]);
            alpha[r] = exp2f(m_r[r] - mn);
            m_r[r] = mn;
        }
        float ls[4] = {0.f, 0.f, 0.f, 0.f};
        #pragma unroll
        for (int ni = 0; ni < 4; ++ni) {
            int colb = ni * 16 + ln;
            #pragma unroll
            for (int r = 0; r < 4; ++r) {
                float p = exp2f(s[ni][r] - m_r[r]);
                ls[r] += p;
                Pslab[((colb >> 3) * 17 + quad * 4 + r) * 8 + (colb & 7)] = f2bf(p);
            }
        }
        #pragma unroll
        for (int mask = 1; mask < 16; mask <<= 1)
            #pragma unroll
            for (int r = 0; r < 4; ++r)
                ls[r] += __shfl_xor(ls[r], mask);
        #pragma unroll
        for (int r = 0; r < 4; ++r) l_r[r] = l_r[r] * alpha[r] + ls[r];
        #pragma unroll
        for (int ni = 0; ni < 16; ++ni)
            #pragma unroll
            for (int r = 0; r < 4; ++r) o[ni][r] *= alpha[r];

        short8 pf0 = *(const short8*)&Pslab[((0 + quad) * 17 + ln) * 8];
        short8 pf1 = *(const short8*)&Pslab[((4 + quad) * 17 + ln) * 8];
        #pragma unroll
        for (int ni = 0; ni < 16; ++ni) {
            const ushort* vb = Vt + (size_t)(ni * 16 + ln) * NROW + gkv + quad * 8;
            o[ni] = MFMA16(pf0, *(const short8*)vb, o[ni]);
            o[ni] = MFMA16(pf1, *(const short8*)(vb + 32), o[ni]);
        }
    }

    __syncthreads();   // all waves done with P slabs; U becomes O_s [w][row][e] bf16
    #pragma unroll
    for (int ni = 0; ni < 16; ++ni)
        #pragma unroll
        for (int r = 0; r < 4; ++r)
            U[w * 4096 + (quad * 4 + r) * 256 + ni * 16 + ln] = f2bf(o[ni][r]);
    if (ln == 0) {
        #pragma unroll
        for (int r = 0; r < 4; ++r) {
            m_s[w * 16 + quad * 4 + r] = m_r[r];
            l_s[w * 16 + quad * 4 + r] = l_r[r];
        }
    }
    __syncthreads();

    // cooperative merge of 4 wave-partials -> one bf16 partial + (m,l)
    const int row = tid >> 4, e0 = (tid & 15) * 16;
    float M = fmaxf(fmaxf(m_s[row], m_s[16 + row]), fmaxf(m_s[32 + row], m_s[48 + row]));
    float sc[4], lsum = 0.f;
    #pragma unroll
    for (int w2 = 0; w2 < 4; ++w2) {
        sc[w2] = exp2f(m_s[w2 * 16 + row] - M);
        lsum += sc[w2] * l_s[w2 * 16 + row];
    }
    const int pblk2 = (b * 128 + qt) * 2 + h;
    if ((tid & 15) == 0)
        *(float2*)(mlbuf + (size_t)pblk2 * 32 + row * 2) = make_float2(M, lsum);
    ushort* dst = Op + (size_t)pblk2 * 4096 + row * 256 + e0;
    #pragma unroll
    for (int c = 0; c < 2; ++c) {
        float acc8[8] = {};
        #pragma unroll
        for (int w2 = 0; w2 < 4; ++w2) {
            short8 v = *(const short8*)&U[w2 * 4096 + row * 256 + e0 + c * 8];
            #pragma unroll
            for (int j = 0; j < 8; ++j)
                acc8[j] += sc[w2] * bf2f((unsigned short)v[j]);
        }
        union { ushort us[8]; uint4 v; } pk;
        #pragma unroll
        for (int j = 0; j < 8; ++j) pk.us[j] = f2bf(acc8[j]);
        *(uint4*)(dst + c * 8) = pk.v;
    }
}

// ---------------- final merge of the 2 kv-half partials ----------------
__global__ __launch_bounds__(256) void attn_merge(
    const ushort* __restrict__ Op, const float* __restrict__ mlbuf, float* __restrict__ out)
{
    const int bid = blockIdx.x, t = threadIdx.x;   // bid: b*128+qt
    const int row = t >> 4, e0 = (t & 15) * 16;
    const size_t qrow = (size_t)(bid >> 7) * NT + (size_t)(bid & 127) * 16 + row;
    float2 s0 = *(const float2*)(mlbuf + (size_t)(bid * 2 + 0) * 32 + row * 2);
    float2 s1 = *(const float2*)(mlbuf + (size_t)(bid * 2 + 1) * 32 + row * 2);
    float M = fmaxf(s0.x, s1.x);
    float sc0 = exp2f(s0.x - M), sc1 = exp2f(s1.x - M);
    float inv = 1.f / (sc0 * s0.y + sc1 * s1.y);
    sc0 *= inv; sc1 *= inv;
    const ushort* p0 = Op + (size_t)(bid * 2 + 0) * 4096 + row * 256 + e0;
    const ushort* p1 = Op + (size_t)(bid * 2 + 1) * 4096 + row * 256 + e0;
    float* op = out + qrow * EDIM + e0;
    #pragma unroll
    for (int c = 0; c < 2; ++c) {
        union { ushort us[8]; uint4 v; } u0, u1;
        u0.v = *(const uint4*)(p0 + c * 8);
        u1.v = *(const uint4*)(p1 + c * 8);
        float vv[8];
        #pragma unroll
        for (int j = 0; j < 8; ++j)
            vv[j] = sc0 * bf2f(u0.us[j]) + sc1 * bf2f(u1.us[j]);
        *(float4*)(op + c * 8)     = make_float4(vv[0], vv[1], vv[2], vv[3]);
        *(float4*)(op + c * 8 + 4) = make_float4(vv[4], vv[5], vv[6], vv[7]);
    }
}

extern "C" void kernel_launch(void* const* d_in, const int* in_sizes, int n_in,
                              void* d_out, int out_size, void* d_ws, size_t ws_size,
                              hipStream_t stream) {
    const float* x  = (const float*)d_in[0];
    const float* Wq = (const float*)d_in[1];
    const float* bq = (const float*)d_in[2];
    const float* Wk = (const float*)d_in[3];
    const float* bk = (const float*)d_in[4];
    const float* Wv = (const float*)d_in[5];
    const float* bv = (const float*)d_in[6];
    float* out = (float*)d_out;

    const size_t NE = (size_t)NB * NT * EDIM;        // 2M elems
    ushort* Qh = (ushort*)d_ws;
    ushort* Ql = Qh + NE;
    ushort* Kh = Ql + NE;
    ushort* Kl = Kh + NE;
    ushort* Vt = Kl + NE;                            // [256][8192]
    ushort* Wqh = Vt + NE;
    ushort* Wql = Wqh + 256 * 1024;
    ushort* Wkh = Wql + 256 * 1024;
    ushort* Wkl = Wkh + 256 * 1024;
    ushort* Wvh = Wkl + 256 * 1024;
    ushort* Op  = Wvh + 256 * 1024;                  // 1024 x 4096 bf16 (8.4 MB)
    float*  mlb = (float*)(Op + (size_t)1024 * 4096);// 1024 x 16 x float2 (128 KB)
    // total ws ~= 32.1 MB

    split_w<<<384, 256, 0, stream>>>(Wq, Wk, Wv, Wqh, Wql, Wkh, Wkl, Wvh);
    qkv_proj<<<dim3(2, 128, 3), 256, 0, stream>>>(x, Wqh, Wql, Wkh, Wkl, Wvh,
                                                  bq, bk, bv, Qh, Ql, Kh, Kl, Vt);
    attn<<<1024, 256, 0, stream>>>(Qh, Ql, Kh, Kl, Vt, Op, mlb);
    attn_merge<<<512, 256, 0, stream>>>(Op, mlb, out);
}

// Round 5
// 360.994 us; speedup vs baseline: 1.0312x; 1.0312x over previous
//
#include <hip/hip_runtime.h>
#include <math.h>

#define IDIM 1024
#define EDIM 256
#define NB 4
#define NT 2048
#define NROW 8192

typedef __attribute__((ext_vector_type(8))) short short8;
typedef __attribute__((ext_vector_type(4))) float f32x4;

#define MFMA16(A,B,C) __builtin_amdgcn_mfma_f32_16x16x32_bf16(A,B,C,0,0,0)
#define GLD16(gsrc, ldst) __builtin_amdgcn_global_load_lds( \
    (const __attribute__((address_space(1))) unsigned int*)(gsrc), \
    (__attribute__((address_space(3))) unsigned int*)(ldst), 16, 0, 0)

__device__ __forceinline__ unsigned short f2bf(float x){
    unsigned u = __builtin_bit_cast(unsigned, x);
    u += 0x7fffu + ((u >> 16) & 1u);
    return (unsigned short)(u >> 16);
}
__device__ __forceinline__ float bf2f(unsigned short h){
    unsigned u = ((unsigned)h) << 16;
    return __builtin_bit_cast(float, u);
}

// ---------------- split W -> W^T hi/lo bf16 ----------------
__global__ __launch_bounds__(256) void split_w(
    const float* __restrict__ Wq, const float* __restrict__ Wk, const float* __restrict__ Wv,
    ushort* __restrict__ Wqh, ushort* __restrict__ Wql,
    ushort* __restrict__ Wkh, ushort* __restrict__ Wkl,
    ushort* __restrict__ Wvh)
{
    int u = blockIdx.x * 256 + threadIdx.x;
    int z   = u >> 15;
    int rem = u & 32767;
    int ko  = rem >> 8;
    int e   = rem & 255;
    const float* W = (z == 0) ? Wq : (z == 1) ? Wk : Wv;
    ushort* Oh = (z == 0) ? Wqh : (z == 1) ? Wkh : Wvh;
    ushort* Ol = (z == 0) ? Wql : Wkl;
    union { ushort us[8]; uint4 v; } hi, lo;
    #pragma unroll
    for (int j = 0; j < 8; ++j) {
        float wv = W[(size_t)(ko * 8 + j) * 256 + e];
        unsigned short h = f2bf(wv);
        hi.us[j] = h;
        lo.us[j] = f2bf(wv - bf2f(h));
    }
    *(uint4*)(Oh + (size_t)e * 1024 + ko * 8) = hi.v;
    if (z < 2) *(uint4*)(Ol + (size_t)e * 1024 + ko * 8) = lo.v;
}

// ---------------- QKV projection: 64x128 tile, fused X-split, GLD16 for W ----------------
__global__ __launch_bounds__(256, 3) void qkv_proj(
    const float* __restrict__ X,
    const ushort* __restrict__ Whq, const ushort* __restrict__ Wlq,
    const ushort* __restrict__ Whk, const ushort* __restrict__ Wlk,
    const ushort* __restrict__ Whv,
    const float* __restrict__ bq, const float* __restrict__ bk, const float* __restrict__ bv,
    ushort* __restrict__ Qh, ushort* __restrict__ Ql,
    ushort* __restrict__ Kh, ushort* __restrict__ Kl,
    ushort* __restrict__ Vt)
{
    __shared__ ushort Ah[259 * 8], Al[259 * 8];   // unit = kq*65 + m (pad 65 vs 64)
    __shared__ ushort Bh[512 * 8], Bl[512 * 8];   // unit = kq*128 + n

    const int tid = threadIdx.x;
    const int lane = tid & 63, w = tid >> 6;
    const int ln = tid & 15, quad = (tid >> 4) & 3;
    const int z = blockIdx.z;
    const int n0 = blockIdx.x * 128, m0 = blockIdx.y * 64;
    const ushort* Wh = (z == 0) ? Whq : (z == 1) ? Whk : Whv;
    const ushort* Wl = (z == 0) ? Wlq : Wlk;

    f32x4 acc[4][2];
    #pragma unroll
    for (int mi = 0; mi < 4; ++mi)
        #pragma unroll
        for (int ni = 0; ni < 2; ++ni) acc[mi][ni] = (f32x4){0.f, 0.f, 0.f, 0.f};

    const int am = tid >> 2, ak8 = (tid & 3) * 8;
    const float* xp = X + (size_t)(m0 + am) * IDIM + ak8;
    const ushort* bsrc0 = Wh + (size_t)(n0 + lane) * IDIM + w * 8;
    const ushort* bsrc1 = Wh + (size_t)(n0 + 64 + lane) * IDIM + w * 8;
    const ushort* blsrc0 = Wl + (size_t)(n0 + lane) * IDIM + w * 8;
    const ushort* blsrc1 = Wl + (size_t)(n0 + 64 + lane) * IDIM + w * 8;
    ushort* bd0 = Bh + (size_t)(w * 128) * 8;
    ushort* bd1 = Bh + (size_t)(w * 128 + 64) * 8;
    ushort* bld0 = Bl + (size_t)(w * 128) * 8;
    ushort* bld1 = Bl + (size_t)(w * 128 + 64) * 8;

    for (int kk = 0; kk < IDIM; kk += 32) {
        GLD16(bsrc0 + kk, bd0);
        GLD16(bsrc1 + kk, bd1);
        if (z < 2) { GLD16(blsrc0 + kk, bld0); GLD16(blsrc1 + kk, bld1); }
        {   // A: read 8 f32 of X, split hi/lo, scatter fragment-major
            float4 a0 = *(const float4*)(xp + kk);
            float4 a1 = *(const float4*)(xp + kk + 4);
            float xv[8] = {a0.x, a0.y, a0.z, a0.w, a1.x, a1.y, a1.z, a1.w};
            union { ushort us[8]; uint4 v; } hi, lo;
            #pragma unroll
            for (int j = 0; j < 8; ++j) {
                unsigned short hh = f2bf(xv[j]);
                hi.us[j] = hh;
                lo.us[j] = f2bf(xv[j] - bf2f(hh));
            }
            int unit = (tid & 3) * 65 + am;
            *(uint4*)(Ah + unit * 8) = hi.v;
            if (z < 2) *(uint4*)(Al + unit * 8) = lo.v;
        }
        __syncthreads();

        short8 ah[4], al4[4];
        #pragma unroll
        for (int mi = 0; mi < 4; ++mi) {
            int au = quad * 65 + mi * 16 + ln;
            ah[mi] = *(const short8*)(Ah + au * 8);
            if (z < 2) al4[mi] = *(const short8*)(Al + au * 8);
        }
        #pragma unroll
        for (int ni = 0; ni < 2; ++ni) {
            int bu = quad * 128 + w * 32 + ni * 16 + ln;
            short8 bh = *(const short8*)(Bh + bu * 8);
            if (z < 2) {
                short8 bl = *(const short8*)(Bl + bu * 8);
                #pragma unroll
                for (int mi = 0; mi < 4; ++mi) {
                    acc[mi][ni] = MFMA16(ah[mi], bh, acc[mi][ni]);
                    acc[mi][ni] = MFMA16(ah[mi], bl, acc[mi][ni]);
                    acc[mi][ni] = MFMA16(al4[mi], bh, acc[mi][ni]);
                }
            } else {
                #pragma unroll
                for (int mi = 0; mi < 4; ++mi)
                    acc[mi][ni] = MFMA16(ah[mi], bh, acc[mi][ni]);
            }
        }
        __syncthreads();
    }

    if (z < 2) {
        ushort* OH = (z == 0) ? Qh : Kh;
        ushort* OL = (z == 0) ? Ql : Kl;
        const float* bias = (z == 0) ? bq : bk;
        const float scale = (z == 0) ? 46.16624130844683f : 1.0f;  // 32*log2(e)
        #pragma unroll
        for (int ni = 0; ni < 2; ++ni) {
            int col = n0 + w * 32 + ni * 16 + ln;
            float bb = bias[col];
            #pragma unroll
            for (int mi = 0; mi < 4; ++mi)
                #pragma unroll
                for (int r = 0; r < 4; ++r) {
                    int row = m0 + mi * 16 + quad * 4 + r;
                    float v = (acc[mi][ni][r] + bb) * scale;
                    unsigned short hh = f2bf(v);
                    OH[(size_t)row * EDIM + col] = hh;
                    OL[(size_t)row * EDIM + col] = f2bf(v - bf2f(hh));
                }
        }
    } else {
        #pragma unroll
        for (int ni = 0; ni < 2; ++ni) {
            int col = n0 + w * 32 + ni * 16 + ln;
            float bb = bv[col];
            #pragma unroll
            for (int mi = 0; mi < 4; ++mi) {
                int rowb = m0 + mi * 16 + quad * 4;
                union { ushort us[4]; uint2 v; } pk;
                #pragma unroll
                for (int r = 0; r < 4; ++r) pk.us[r] = f2bf(acc[mi][ni][r] + bb);
                *(uint2*)(Vt + (size_t)col * NROW + rowb) = pk.v;
            }
        }
    }
}

// ---------------- attention: wave = 16 q x 256 kv, kv-split 8, in-block pair merge ----------------
// 1024 blocks x 4 waves. launch_bounds (256,3): ~170-reg budget -> NO scratch spills
// (R4's (256,4) capped at 128 regs and spilled o[16] -> 500 MB HBM scratch traffic).
__global__ __launch_bounds__(256, 3) void attn(
    const ushort* __restrict__ Qh, const ushort* __restrict__ Ql,
    const ushort* __restrict__ Kh, const ushort* __restrict__ Kl,
    const ushort* __restrict__ Vt, ushort* __restrict__ Op, float* __restrict__ mlbuf)
{
    __shared__ ushort U[16384];            // front 4352: P slabs; whole: bf16 O_s reuse
    __shared__ float m_s[64], l_s[64];
    const int tid = threadIdx.x;
    const int ln = tid & 15, quad = (tid >> 4) & 3, w = tid >> 6;
    ushort* Pslab = U + w * 1088;          // unit = ko*17 + m

    const int id = blockIdx.x;
    const int b  = (id >> 1) & 3;          // XCD-locked batch
    const int h  = id & 1;                 // kv half (XCD-locked too)
    const int qt = id >> 3;                // 0..127
    const size_t qrow0 = (size_t)b * NT + (size_t)qt * 16;
    const int kvs = b * NT + h * 1024 + w * 256;

    const ushort* qbase  = Qh + (qrow0 + ln) * EDIM + quad * 8;
    const ushort* qlbase = Ql + (qrow0 + ln) * EDIM + quad * 8;

    float m_r[4], l_r[4];
    #pragma unroll
    for (int r = 0; r < 4; ++r) { m_r[r] = -3e38f; l_r[r] = 0.f; }
    f32x4 o[16];
    #pragma unroll
    for (int ni = 0; ni < 16; ++ni) o[ni] = (f32x4){0.f, 0.f, 0.f, 0.f};

    for (int t = 0; t < 4; ++t) {
        const int gkv = kvs + t * 64;
        f32x4 s[4];
        #pragma unroll
        for (int ni = 0; ni < 4; ++ni) s[ni] = (f32x4){0.f, 0.f, 0.f, 0.f};

        #pragma unroll
        for (int kc = 0; kc < 8; ++kc) {
            short8 qh8 = *(const short8*)(qbase + kc * 32);
            short8 ql8 = *(const short8*)(qlbase + kc * 32);
            #pragma unroll
            for (int ni = 0; ni < 4; ++ni) {
                size_t off = (size_t)(gkv + ni * 16 + ln) * EDIM + kc * 32 + quad * 8;
                short8 bh = *(const short8*)(Kh + off);
                short8 bl = *(const short8*)(Kl + off);
                s[ni] = MFMA16(qh8, bh, s[ni]);
                s[ni] = MFMA16(qh8, bl, s[ni]);
                s[ni] = MFMA16(ql8, bh, s[ni]);
            }
        }

        float mt[4];
        #pragma unroll
        for (int r = 0; r < 4; ++r)
            mt[r] = fmaxf(fmaxf(s[0][r], s[1][r]), fmaxf(s[2][r], s[3][r]));
        #pragma unroll
        for (int mask = 1; mask < 16; mask <<= 1)
            #pragma unroll
            for (int r = 0; r < 4; ++r)
                mt[r] = fmaxf(mt[r], __shfl_xor(mt[r], mask));
        float alpha[4];
        #pragma unroll
        for (int r = 0; r < 4; ++r) {
            float mn = fmaxf(m_r[r], mt[r]);
            alpha[r] = exp2f(m_r[r] - mn);
            m_r[r] = mn;
        }
        float ls[4] = {0.f, 0.f, 0.f, 0.f};
        #pragma unroll
        for (int ni = 0; ni < 4; ++ni) {
            int colb = ni * 16 + ln;
            #pragma unroll
            for (int r = 0; r < 4; ++r) {
                float p = exp2f(s[ni][r] - m_r[r]);
                ls[r] += p;
                Pslab[((colb >> 3) * 17 + quad * 4 + r) * 8 + (colb & 7)] = f2bf(p);
            }
        }
        #pragma unroll
        for (int mask = 1; mask < 16; mask <<= 1)
            #pragma unroll
            for (int r = 0; r < 4; ++r)
                ls[r] += __shfl_xor(ls[r], mask);
        #pragma unroll
        for (int r = 0; r < 4; ++r) l_r[r] = l_r[r] * alpha[r] + ls[r];
        #pragma unroll
        for (int ni = 0; ni < 16; ++ni)
            #pragma unroll
            for (int r = 0; r < 4; ++r) o[ni][r] *= alpha[r];

        short8 pf0 = *(const short8*)&Pslab[((0 + quad) * 17 + ln) * 8];
        short8 pf1 = *(const short8*)&Pslab[((4 + quad) * 17 + ln) * 8];
        #pragma unroll
        for (int ni = 0; ni < 16; ++ni) {
            const ushort* vb = Vt + (size_t)(ni * 16 + ln) * NROW + gkv + quad * 8;
            o[ni] = MFMA16(pf0, *(const short8*)vb, o[ni]);
            o[ni] = MFMA16(pf1, *(const short8*)(vb + 32), o[ni]);
        }
    }

    __syncthreads();   // all waves done with P slabs; U becomes O_s [w][row][e] bf16
    #pragma unroll
    for (int ni = 0; ni < 16; ++ni)
        #pragma unroll
        for (int r = 0; r < 4; ++r)
            U[w * 4096 + (quad * 4 + r) * 256 + ni * 16 + ln] = f2bf(o[ni][r]);
    if (ln == 0) {
        #pragma unroll
        for (int r = 0; r < 4; ++r) {
            m_s[w * 16 + quad * 4 + r] = m_r[r];
            l_s[w * 16 + quad * 4 + r] = l_r[r];
        }
    }
    __syncthreads();

    // cooperative merge of 4 wave-partials -> one bf16 partial + (m,l)
    const int row = tid >> 4, e0 = (tid & 15) * 16;
    float M = fmaxf(fmaxf(m_s[row], m_s[16 + row]), fmaxf(m_s[32 + row], m_s[48 + row]));
    float sc[4], lsum = 0.f;
    #pragma unroll
    for (int w2 = 0; w2 < 4; ++w2) {
        sc[w2] = exp2f(m_s[w2 * 16 + row] - M);
        lsum += sc[w2] * l_s[w2 * 16 + row];
    }
    const int pblk2 = (b * 128 + qt) * 2 + h;
    if ((tid & 15) == 0)
        *(float2*)(mlbuf + (size_t)pblk2 * 32 + row * 2) = make_float2(M, lsum);
    ushort* dst = Op + (size_t)pblk2 * 4096 + row * 256 + e0;
    #pragma unroll
    for (int c = 0; c < 2; ++c) {
        float acc8[8] = {};
        #pragma unroll
        for (int w2 = 0; w2 < 4; ++w2) {
            short8 v = *(const short8*)&U[w2 * 4096 + row * 256 + e0 + c * 8];
            #pragma unroll
            for (int j = 0; j < 8; ++j)
                acc8[j] += sc[w2] * bf2f((unsigned short)v[j]);
        }
        union { ushort us[8]; uint4 v; } pk;
        #pragma unroll
        for (int j = 0; j < 8; ++j) pk.us[j] = f2bf(acc8[j]);
        *(uint4*)(dst + c * 8) = pk.v;
    }
}

// ---------------- final merge of the 2 kv-half partials ----------------
__global__ __launch_bounds__(256) void attn_merge(
    const ushort* __restrict__ Op, const float* __restrict__ mlbuf, float* __restrict__ out)
{
    const int bid = blockIdx.x, t = threadIdx.x;   // bid: b*128+qt
    const int row = t >> 4, e0 = (t & 15) * 16;
    const size_t qrow = (size_t)(bid >> 7) * NT + (size_t)(bid & 127) * 16 + row;
    float2 s0 = *(const float2*)(mlbuf + (size_t)(bid * 2 + 0) * 32 + row * 2);
    float2 s1 = *(const float2*)(mlbuf + (size_t)(bid * 2 + 1) * 32 + row * 2);
    float M = fmaxf(s0.x, s1.x);
    float sc0 = exp2f(s0.x - M), sc1 = exp2f(s1.x - M);
    float inv = 1.f / (sc0 * s0.y + sc1 * s1.y);
    sc0 *= inv; sc1 *= inv;
    const ushort* p0 = Op + (size_t)(bid * 2 + 0) * 4096 + row * 256 + e0;
    const ushort* p1 = Op + (size_t)(bid * 2 + 1) * 4096 + row * 256 + e0;
    float* op = out + qrow * EDIM + e0;
    #pragma unroll
    for (int c = 0; c < 2; ++c) {
        union { ushort us[8]; uint4 v; } u0, u1;
        u0.v = *(const uint4*)(p0 + c * 8);
        u1.v = *(const uint4*)(p1 + c * 8);
        float vv[8];
        #pragma unroll
        for (int j = 0; j < 8; ++j)
            vv[j] = sc0 * bf2f(u0.us[j]) + sc1 * bf2f(u1.us[j]);
        *(float4*)(op + c * 8)     = make_float4(vv[0], vv[1], vv[2], vv[3]);
        *(float4*)(op + c * 8 + 4) = make_float4(vv[4], vv[5], vv[6], vv[7]);
    }
}

extern "C" void kernel_launch(void* const* d_in, const int* in_sizes, int n_in,
                              void* d_out, int out_size, void* d_ws, size_t ws_size,
                              hipStream_t stream) {
    const float* x  = (const float*)d_in[0];
    const float* Wq = (const float*)d_in[1];
    const float* bq = (const float*)d_in[2];
    const float* Wk = (const float*)d_in[3];
    const float* bk = (const float*)d_in[4];
    const float* Wv = (const float*)d_in[5];
    const float* bv = (const float*)d_in[6];
    float* out = (float*)d_out;

    const size_t NE = (size_t)NB * NT * EDIM;        // 2M elems
    ushort* Qh = (ushort*)d_ws;
    ushort* Ql = Qh + NE;
    ushort* Kh = Ql + NE;
    ushort* Kl = Kh + NE;
    ushort* Vt = Kl + NE;                            // [256][8192]
    ushort* Wqh = Vt + NE;
    ushort* Wql = Wqh + 256 * 1024;
    ushort* Wkh = Wql + 256 * 1024;
    ushort* Wkl = Wkh + 256 * 1024;
    ushort* Wvh = Wkl + 256 * 1024;
    ushort* Op  = Wvh + 256 * 1024;                  // 1024 x 4096 bf16 (8.4 MB)
    float*  mlb = (float*)(Op + (size_t)1024 * 4096);// 1024 x 16 x float2 (128 KB)
    // total ws ~= 32.1 MB

    split_w<<<384, 256, 0, stream>>>(Wq, Wk, Wv, Wqh, Wql, Wkh, Wkl, Wvh);
    qkv_proj<<<dim3(2, 128, 3), 256, 0, stream>>>(x, Wqh, Wql, Wkh, Wkl, Wvh,
                                                  bq, bk, bv, Qh, Ql, Kh, Kl, Vt);
    attn<<<1024, 256, 0, stream>>>(Qh, Ql, Kh, Kl, Vt, Op, mlb);
    attn_merge<<<512, 256, 0, stream>>>(Op, mlb, out);
}

// Round 6
// 212.791 us; speedup vs baseline: 1.7494x; 1.6965x over previous
//
#include <hip/hip_runtime.h>
#include <math.h>

#define IDIM 1024
#define EDIM 256
#define NB 4
#define NT 2048
#define NROW 8192

typedef __attribute__((ext_vector_type(8))) short short8;
typedef __attribute__((ext_vector_type(4))) float f32x4;

#define MFMA16(A,B,C) __builtin_amdgcn_mfma_f32_16x16x32_bf16(A,B,C,0,0,0)
#define GLD16(gsrc, ldst) __builtin_amdgcn_global_load_lds( \
    (const __attribute__((address_space(1))) unsigned int*)(gsrc), \
    (__attribute__((address_space(3))) unsigned int*)(ldst), 16, 0, 0)

__device__ __forceinline__ unsigned short f2bf(float x){
    unsigned u = __builtin_bit_cast(unsigned, x);
    u += 0x7fffu + ((u >> 16) & 1u);
    return (unsigned short)(u >> 16);
}
__device__ __forceinline__ float bf2f(unsigned short h){
    unsigned u = ((unsigned)h) << 16;
    return __builtin_bit_cast(float, u);
}

// ---------------- split W -> W^T hi/lo bf16 ----------------
__global__ __launch_bounds__(256) void split_w(
    const float* __restrict__ Wq, const float* __restrict__ Wk, const float* __restrict__ Wv,
    ushort* __restrict__ Wqh, ushort* __restrict__ Wql,
    ushort* __restrict__ Wkh, ushort* __restrict__ Wkl,
    ushort* __restrict__ Wvh)
{
    int u = blockIdx.x * 256 + threadIdx.x;
    int z   = u >> 15;
    int rem = u & 32767;
    int ko  = rem >> 8;
    int e   = rem & 255;
    const float* W = (z == 0) ? Wq : (z == 1) ? Wk : Wv;
    ushort* Oh = (z == 0) ? Wqh : (z == 1) ? Wkh : Wvh;
    ushort* Ol = (z == 0) ? Wql : Wkl;
    union { ushort us[8]; uint4 v; } hi, lo;
    #pragma unroll
    for (int j = 0; j < 8; ++j) {
        float wv = W[(size_t)(ko * 8 + j) * 256 + e];
        unsigned short h = f2bf(wv);
        hi.us[j] = h;
        lo.us[j] = f2bf(wv - bf2f(h));
    }
    *(uint4*)(Oh + (size_t)e * 1024 + ko * 8) = hi.v;
    if (z < 2) *(uint4*)(Ol + (size_t)e * 1024 + ko * 8) = lo.v;
}

// ---------------- QKV projection: 64x128 tile, fused X-split, GLD16 for W ----------------
__global__ __launch_bounds__(256, 3) void qkv_proj(
    const float* __restrict__ X,
    const ushort* __restrict__ Whq, const ushort* __restrict__ Wlq,
    const ushort* __restrict__ Whk, const ushort* __restrict__ Wlk,
    const ushort* __restrict__ Whv,
    const float* __restrict__ bq, const float* __restrict__ bk, const float* __restrict__ bv,
    ushort* __restrict__ Qh, ushort* __restrict__ Ql,
    ushort* __restrict__ Kh, ushort* __restrict__ Kl,
    ushort* __restrict__ Vt)
{
    __shared__ ushort Ah[259 * 8], Al[259 * 8];   // unit = kq*65 + m (pad 65 vs 64)
    __shared__ ushort Bh[512 * 8], Bl[512 * 8];   // unit = kq*128 + n

    const int tid = threadIdx.x;
    const int lane = tid & 63, w = tid >> 6;
    const int ln = tid & 15, quad = (tid >> 4) & 3;
    const int z = blockIdx.z;
    const int n0 = blockIdx.x * 128, m0 = blockIdx.y * 64;
    const ushort* Wh = (z == 0) ? Whq : (z == 1) ? Whk : Whv;
    const ushort* Wl = (z == 0) ? Wlq : Wlk;

    f32x4 acc[4][2];
    #pragma unroll
    for (int mi = 0; mi < 4; ++mi)
        #pragma unroll
        for (int ni = 0; ni < 2; ++ni) acc[mi][ni] = (f32x4){0.f, 0.f, 0.f, 0.f};

    const int am = tid >> 2, ak8 = (tid & 3) * 8;
    const float* xp = X + (size_t)(m0 + am) * IDIM + ak8;
    const ushort* bsrc0 = Wh + (size_t)(n0 + lane) * IDIM + w * 8;
    const ushort* bsrc1 = Wh + (size_t)(n0 + 64 + lane) * IDIM + w * 8;
    const ushort* blsrc0 = Wl + (size_t)(n0 + lane) * IDIM + w * 8;
    const ushort* blsrc1 = Wl + (size_t)(n0 + 64 + lane) * IDIM + w * 8;
    ushort* bd0 = Bh + (size_t)(w * 128) * 8;
    ushort* bd1 = Bh + (size_t)(w * 128 + 64) * 8;
    ushort* bld0 = Bl + (size_t)(w * 128) * 8;
    ushort* bld1 = Bl + (size_t)(w * 128 + 64) * 8;

    for (int kk = 0; kk < IDIM; kk += 32) {
        GLD16(bsrc0 + kk, bd0);
        GLD16(bsrc1 + kk, bd1);
        if (z < 2) { GLD16(blsrc0 + kk, bld0); GLD16(blsrc1 + kk, bld1); }
        {
            float4 a0 = *(const float4*)(xp + kk);
            float4 a1 = *(const float4*)(xp + kk + 4);
            float xv[8] = {a0.x, a0.y, a0.z, a0.w, a1.x, a1.y, a1.z, a1.w};
            union { ushort us[8]; uint4 v; } hi, lo;
            #pragma unroll
            for (int j = 0; j < 8; ++j) {
                unsigned short hh = f2bf(xv[j]);
                hi.us[j] = hh;
                lo.us[j] = f2bf(xv[j] - bf2f(hh));
            }
            int unit = (tid & 3) * 65 + am;
            *(uint4*)(Ah + unit * 8) = hi.v;
            if (z < 2) *(uint4*)(Al + unit * 8) = lo.v;
        }
        __syncthreads();

        short8 ah[4], al4[4];
        #pragma unroll
        for (int mi = 0; mi < 4; ++mi) {
            int au = quad * 65 + mi * 16 + ln;
            ah[mi] = *(const short8*)(Ah + au * 8);
            if (z < 2) al4[mi] = *(const short8*)(Al + au * 8);
        }
        #pragma unroll
        for (int ni = 0; ni < 2; ++ni) {
            int bu = quad * 128 + w * 32 + ni * 16 + ln;
            short8 bh = *(const short8*)(Bh + bu * 8);
            if (z < 2) {
                short8 bl = *(const short8*)(Bl + bu * 8);
                #pragma unroll
                for (int mi = 0; mi < 4; ++mi) {
                    acc[mi][ni] = MFMA16(ah[mi], bh, acc[mi][ni]);
                    acc[mi][ni] = MFMA16(ah[mi], bl, acc[mi][ni]);
                    acc[mi][ni] = MFMA16(al4[mi], bh, acc[mi][ni]);
                }
            } else {
                #pragma unroll
                for (int mi = 0; mi < 4; ++mi)
                    acc[mi][ni] = MFMA16(ah[mi], bh, acc[mi][ni]);
            }
        }
        __syncthreads();
    }

    if (z < 2) {
        ushort* OH = (z == 0) ? Qh : Kh;
        ushort* OL = (z == 0) ? Ql : Kl;
        const float* bias = (z == 0) ? bq : bk;
        const float scale = (z == 0) ? 46.16624130844683f : 1.0f;  // 32*log2(e)
        #pragma unroll
        for (int ni = 0; ni < 2; ++ni) {
            int col = n0 + w * 32 + ni * 16 + ln;
            float bb = bias[col];
            #pragma unroll
            for (int mi = 0; mi < 4; ++mi)
                #pragma unroll
                for (int r = 0; r < 4; ++r) {
                    int row = m0 + mi * 16 + quad * 4 + r;
                    float v = (acc[mi][ni][r] + bb) * scale;
                    unsigned short hh = f2bf(v);
                    OH[(size_t)row * EDIM + col] = hh;
                    OL[(size_t)row * EDIM + col] = f2bf(v - bf2f(hh));
                }
        }
    } else {
        #pragma unroll
        for (int ni = 0; ni < 2; ++ni) {
            int col = n0 + w * 32 + ni * 16 + ln;
            float bb = bv[col];
            #pragma unroll
            for (int mi = 0; mi < 4; ++mi) {
                int rowb = m0 + mi * 16 + quad * 4;
                union { ushort us[4]; uint2 v; } pk;
                #pragma unroll
                for (int r = 0; r < 4; ++r) pk.us[r] = f2bf(acc[mi][ni][r] + bb);
                *(uint2*)(Vt + (size_t)col * NROW + rowb) = pk.v;
            }
        }
    }
}

// ---------------- attention: block = 64 q x 512 kv, waves split q; GLD16-staged K/V ----------------
// 512 blocks x 4 waves. K/V staged cooperatively (each byte feeds 4 waves, no VGPR
// load destinations -> no spills). Wave owns 16 q rows end-to-end; partials to Op.
__global__ __launch_bounds__(256, 2) void attn(
    const ushort* __restrict__ Qh, const ushort* __restrict__ Ql,
    const ushort* __restrict__ Kh, const ushort* __restrict__ Kl,
    const ushort* __restrict__ Vt, ushort* __restrict__ Op, float* __restrict__ mlbuf)
{
    __shared__ ushort KVbuf[4096];     // 8 KB: K chunk (hi 4K @0, lo 4K @2048u) / V chunk
    __shared__ ushort Qls[16384];      // 32 KB: wave w at w*4096 (unit = ko*16+ln)
    __shared__ ushort Pall[4 * 1088];  // per-wave P slab (unit = ko*17+row)

    const int tid = threadIdx.x;
    const int lane = tid & 63;
    const int ln = tid & 15, quad = (tid >> 4) & 3, w = tid >> 6;
    ushort* Qls_w = Qls + w * 4096;
    ushort* Pw = Pall + w * 1088;

    const int id = blockIdx.x;              // 512 = qt(32) x [b(4) x kvq(4)]
    const int cls = id & 15;
    const int b = cls >> 2, kvq = cls & 3;  // id%8 spreads (b,kvq) classes over XCDs
    const int qt = id >> 4;
    const int qrow0w = b * NT + qt * 64 + w * 16;
    const int kvbase = b * NT + kvq * 512;

    // Q hi fragments resident; Q lo staged to wave-private LDS once
    short8 qh8[8];
    #pragma unroll
    for (int kc = 0; kc < 8; ++kc)
        qh8[kc] = *(const short8*)(Qh + (size_t)(qrow0w + ln) * EDIM + kc * 32 + quad * 8);
    #pragma unroll
    for (int i = 0; i < 8; ++i) {
        int u = i * 64 + lane;              // unit = ko*16 + ln2
        int ko = u >> 4, ln2 = u & 15;
        *(uint4*)(Qls_w + u * 8) =
            *(const uint4*)(Ql + (size_t)(qrow0w + ln2) * EDIM + ko * 8);
    }

    float m_r[4], l_r[4];
    #pragma unroll
    for (int r = 0; r < 4; ++r) { m_r[r] = -3e38f; l_r[r] = 0.f; }
    f32x4 o[16];
    #pragma unroll
    for (int ni = 0; ni < 16; ++ni) o[ni] = (f32x4){0.f, 0.f, 0.f, 0.f};

    for (int t = 0; t < 8; ++t) {
        const int kv0 = kvbase + t * 64;
        f32x4 s[4];
        #pragma unroll
        for (int ni = 0; ni < 4; ++ni) s[ni] = (f32x4){0.f, 0.f, 0.f, 0.f};

        // ---- S = Q'.K^T : 8 e-chunks of 32, K via global_load_lds ----
        #pragma unroll
        for (int kc = 0; kc < 8; ++kc) {
            size_t goff = (size_t)(kv0 + w * 16 + (lane & 15)) * EDIM
                          + kc * 32 + (lane >> 4) * 8;
            GLD16(Kh + goff, KVbuf + w * 512);
            GLD16(Kl + goff, KVbuf + 2048 + w * 512);
            __syncthreads();
            short8 ql8 = *(const short8*)(Qls_w + ((kc * 4 + quad) * 16 + ln) * 8);
            #pragma unroll
            for (int ni = 0; ni < 4; ++ni) {
                short8 bh = *(const short8*)(KVbuf + (ni * 64 + quad * 16 + ln) * 8);
                short8 bl = *(const short8*)(KVbuf + 2048 + (ni * 64 + quad * 16 + ln) * 8);
                s[ni] = MFMA16(qh8[kc], bh, s[ni]);
                s[ni] = MFMA16(qh8[kc], bl, s[ni]);
                s[ni] = MFMA16(ql8, bh, s[ni]);
            }
            __syncthreads();
        }

        // ---- online softmax (wave-local) ----
        float mt[4];
        #pragma unroll
        for (int r = 0; r < 4; ++r)
            mt[r] = fmaxf(fmaxf(s[0][r], s[1][r]), fmaxf(s[2][r], s[3][r]));
        #pragma unroll
        for (int mask = 1; mask < 16; mask <<= 1)
            #pragma unroll
            for (int r = 0; r < 4; ++r)
                mt[r] = fmaxf(mt[r], __shfl_xor(mt[r], mask));
        float alpha[4];
        #pragma unroll
        for (int r = 0; r < 4; ++r) {
            float mn = fmaxf(m_r[r], mt[r]);
            alpha[r] = exp2f(m_r[r] - mn);
            m_r[r] = mn;
        }
        float ls[4] = {0.f, 0.f, 0.f, 0.f};
        #pragma unroll
        for (int ni = 0; ni < 4; ++ni) {
            int colb = ni * 16 + ln;
            #pragma unroll
            for (int r = 0; r < 4; ++r) {
                float p = exp2f(s[ni][r] - m_r[r]);
                ls[r] += p;
                Pw[((colb >> 3) * 17 + quad * 4 + r) * 8 + (colb & 7)] = f2bf(p);
            }
        }
        #pragma unroll
        for (int mask = 1; mask < 16; mask <<= 1)
            #pragma unroll
            for (int r = 0; r < 4; ++r)
                ls[r] += __shfl_xor(ls[r], mask);
        #pragma unroll
        for (int r = 0; r < 4; ++r) l_r[r] = l_r[r] * alpha[r] + ls[r];
        #pragma unroll
        for (int ni = 0; ni < 16; ++ni)
            #pragma unroll
            for (int r = 0; r < 4; ++r) o[ni][r] *= alpha[r];

        // ---- O += P.V : V via global_load_lds, 4 e-chunks of 64 ----
        short8 apk0 = *(const short8*)(Pw + (quad * 17 + ln) * 8);
        short8 apk1 = *(const short8*)(Pw + ((4 + quad) * 17 + ln) * 8);
        #pragma unroll
        for (int vs = 0; vs < 4; ++vs) {
            size_t gv = (size_t)(vs * 64 + w * 16 + (lane & 15)) * NROW
                        + kv0 + (lane >> 4) * 8;
            GLD16(Vt + gv, KVbuf + w * 1024);
            GLD16(Vt + gv + 32, KVbuf + w * 1024 + 512);
            __syncthreads();
            #pragma unroll
            for (int ni = 0; ni < 4; ++ni) {
                short8 v0 = *(const short8*)(KVbuf + (ni * 128 + quad * 16 + ln) * 8);
                short8 v1 = *(const short8*)(KVbuf + (ni * 128 + 64 + quad * 16 + ln) * 8);
                o[vs * 4 + ni] = MFMA16(apk0, v0, o[vs * 4 + ni]);
                o[vs * 4 + ni] = MFMA16(apk1, v1, o[vs * 4 + ni]);
            }
            __syncthreads();
        }
    }

    // ---- epilogue: wave owns rows, write bf16 partial + (m,l) ----
    const int p = (b * 32 + qt) * 4 + kvq;
    if (ln == 0) {
        #pragma unroll
        for (int r = 0; r < 4; ++r) {
            int row = w * 16 + quad * 4 + r;
            *(float2*)(mlbuf + ((size_t)p * 64 + row) * 2) = make_float2(m_r[r], l_r[r]);
        }
    }
    #pragma unroll
    for (int ni = 0; ni < 16; ++ni)
        #pragma unroll
        for (int r = 0; r < 4; ++r) {
            int row = w * 16 + quad * 4 + r;
            Op[(size_t)p * 16384 + row * 256 + ni * 16 + ln] = f2bf(o[ni][r]);
        }
}

// ---------------- final merge of 4 kv-quarter partials ----------------
__global__ __launch_bounds__(256) void attn_merge(
    const ushort* __restrict__ Op, const float* __restrict__ mlbuf, float* __restrict__ out)
{
    const int bid = blockIdx.x, t = threadIdx.x;   // 512 blocks: b(4) x qt(32) x rg(4)
    const int b = bid >> 7, qt = (bid >> 2) & 31, rg = bid & 3;
    const int row = rg * 16 + (t >> 4);
    const int e0 = (t & 15) * 16;
    const int pb = (b * 32 + qt) * 4;
    float mv[4], lv[4];
    float M = -3e38f;
    #pragma unroll
    for (int w2 = 0; w2 < 4; ++w2) {
        float2 ml = *(const float2*)(mlbuf + ((size_t)(pb + w2) * 64 + row) * 2);
        mv[w2] = ml.x; lv[w2] = ml.y;
        M = fmaxf(M, ml.x);
    }
    float sc[4], denom = 0.f;
    #pragma unroll
    for (int w2 = 0; w2 < 4; ++w2) {
        sc[w2] = exp2f(mv[w2] - M);
        denom += sc[w2] * lv[w2];
    }
    float inv = 1.0f / denom;
    #pragma unroll
    for (int w2 = 0; w2 < 4; ++w2) sc[w2] *= inv;

    float acc[16] = {};
    #pragma unroll
    for (int w2 = 0; w2 < 4; ++w2) {
        const ushort* src = Op + (size_t)(pb + w2) * 16384 + row * 256 + e0;
        #pragma unroll
        for (int c = 0; c < 2; ++c) {
            union { ushort us[8]; uint4 v; } u;
            u.v = *(const uint4*)(src + c * 8);
            #pragma unroll
            for (int j = 0; j < 8; ++j)
                acc[c * 8 + j] += sc[w2] * bf2f(u.us[j]);
        }
    }
    float* op = out + ((size_t)b * NT + qt * 64 + row) * EDIM + e0;
    #pragma unroll
    for (int g = 0; g < 4; ++g)
        *(float4*)(op + g * 4) = make_float4(acc[g*4], acc[g*4+1], acc[g*4+2], acc[g*4+3]);
}

extern "C" void kernel_launch(void* const* d_in, const int* in_sizes, int n_in,
                              void* d_out, int out_size, void* d_ws, size_t ws_size,
                              hipStream_t stream) {
    const float* x  = (const float*)d_in[0];
    const float* Wq = (const float*)d_in[1];
    const float* bq = (const float*)d_in[2];
    const float* Wk = (const float*)d_in[3];
    const float* bk = (const float*)d_in[4];
    const float* Wv = (const float*)d_in[5];
    const float* bv = (const float*)d_in[6];
    float* out = (float*)d_out;

    const size_t NE = (size_t)NB * NT * EDIM;        // 2M elems
    ushort* Qh = (ushort*)d_ws;
    ushort* Ql = Qh + NE;
    ushort* Kh = Ql + NE;
    ushort* Kl = Kh + NE;
    ushort* Vt = Kl + NE;                            // [256][8192]
    ushort* Wqh = Vt + NE;
    ushort* Wql = Wqh + 256 * 1024;
    ushort* Wkh = Wql + 256 * 1024;
    ushort* Wkl = Wkh + 256 * 1024;
    ushort* Wvh = Wkl + 256 * 1024;
    ushort* Op  = Wvh + 256 * 1024;                  // 512 partials x 64 x 256 bf16 (16.8 MB)
    float*  mlb = (float*)(Op + (size_t)512 * 16384);// 512 x 64 x float2 (256 KB)
    // total ws ~= 39.6 MB

    split_w<<<384, 256, 0, stream>>>(Wq, Wk, Wv, Wqh, Wql, Wkh, Wkl, Wvh);
    qkv_proj<<<dim3(2, 128, 3), 256, 0, stream>>>(x, Wqh, Wql, Wkh, Wkl, Wvh,
                                                  bq, bk, bv, Qh, Ql, Kh, Kl, Vt);
    attn<<<512, 256, 0, stream>>>(Qh, Ql, Kh, Kl, Vt, Op, mlb);
    attn_merge<<<512, 256, 0, stream>>>(Op, mlb, out);
}